// Round 1
// baseline (2755.660 us; speedup 1.0000x reference)
//
#include <hip/hip_runtime.h>

#define NBLK 256
#define NTHR 512

typedef __attribute__((ext_vector_type(8))) short s16x8;
typedef __attribute__((ext_vector_type(8))) __bf16 bf16x8;
typedef __attribute__((ext_vector_type(4))) float f32x4;

__device__ __forceinline__ ushort f2bf(float f) {
  uint u = __float_as_uint(f);
  return (ushort)((u + 0x7FFFu + ((u >> 16) & 1u)) >> 16);  // RNE
}
__device__ __forceinline__ float bf2f(ushort s) {
  return __uint_as_float(((uint)s) << 16);
}
__device__ __forceinline__ float sigm(float x) { return 1.f / (1.f + __expf(-x)); }
__device__ __forceinline__ float tanhf_(float x) {
  x = fminf(9.f, fmaxf(-9.f, x));
  float e = __expf(2.f * x);
  return (e - 1.f) / (e + 1.f);
}

// ---------------- init: zero h ping-pong slot 0 + barrier ----------------
__global__ void init_k(uint* __restrict__ hbuf0, uint* __restrict__ bar) {
  int i = blockIdx.x * blockDim.x + threadIdx.x;
  if (i < 131072) hbuf0[i] = 0u;  // 2*256*512 bf16 = 131072 uints
  if (i < 64) bar[i] = 0u;
}

// ---------------- transpose/concat x,y -> xyT[t][b][0:512] bf16 ----------------
__global__ void xyt_k(const float* __restrict__ x, const float* __restrict__ y,
                      ushort* __restrict__ xyT) {
  int idx = blockIdx.x * blockDim.x + threadIdx.x;  // exactly 2^24 threads
  int t = idx >> 17;
  int rem = idx & 131071;
  int b = rem >> 9;
  int d = rem & 511;
  float v = (d < 256) ? x[((size_t)b * 256 + d) * 128 + t]
                      : y[((size_t)b * 256 + (d - 256)) * 128 + t];
  xyT[idx] = f2bf(v);
}

// ---------------- device-scope grid barrier ----------------
__device__ __forceinline__ void grid_sync(uint* bar) {
  __syncthreads();
  if (threadIdx.x == 0) {
    uint g = __hip_atomic_load(bar + 32, __ATOMIC_RELAXED, __HIP_MEMORY_SCOPE_AGENT);
    uint t = __hip_atomic_fetch_add(bar, 1u, __ATOMIC_ACQ_REL, __HIP_MEMORY_SCOPE_AGENT);
    if (t == NBLK - 1) {
      __hip_atomic_store(bar, 0u, __ATOMIC_RELAXED, __HIP_MEMORY_SCOPE_AGENT);
      __hip_atomic_store(bar + 32, g + 1u, __ATOMIC_RELEASE, __HIP_MEMORY_SCOPE_AGENT);
    } else {
      while (__hip_atomic_load(bar + 32, __ATOMIC_ACQUIRE, __HIP_MEMORY_SCOPE_AGENT) == g) {
        __builtin_amdgcn_s_sleep(1);
      }
    }
  }
  __syncthreads();
}

// ---------------- persistent sequential LSTM kernel (layer 1 only) ----------------
// grid 256 = s(2) x colgroup(16) x rowtile(8); block 512 thr = 8 waves.
// Block owns rows [m0,m0+32) x h-cols [j0,j0+32) of stream s.
// Waves 0..5: gate panels (f,i,o) x (2 halves of 16 cols), K=1024.
// Waves 6..7: candidate panels, K=768.
__launch_bounds__(NTHR, 2)
__global__ void seq_k(const ushort* __restrict__ xyT, ushort* __restrict__ hbuf,
                      ushort* __restrict__ hist,
                      const float* __restrict__ WTg, const float* __restrict__ WFg,
                      const float* __restrict__ WTc, const float* __restrict__ WFc,
                      const float* __restrict__ bTg, const float* __restrict__ bFg,
                      const float* __restrict__ bTc, const float* __restrict__ bFc,
                      uint* bar) {
  extern __shared__ char smem[];              // [0,65536): A tile [32][2048B] swizzled
  float* sAcc = (float*)(smem + 65536);       // [8][32][16] f32

  const int tid = threadIdx.x;
  const int bid = blockIdx.x;
  const int s = bid & 1;
  const int j0 = ((bid >> 1) & 15) * 32;
  const int m0 = (bid >> 5) * 32;
  const int w = tid >> 6;
  const int l = tid & 63;
  const int l15 = l & 15;
  const int q16 = (l >> 4) * 16;              // byte offset of k-octet
  const bool isGate = (w < 6);

  // ---- persistent weight fragments in VGPRs (layer 1 = offset 1) ----
  s16x8 wreg[32];
  if (isGate) {
    const int gt = w >> 1, half = w & 1;
    const float* Wp = ((s == 0) ? WTg : WFg) + 1572864
                    + ((size_t)(gt * 512 + j0 + half * 16 + l15)) * 1024 + (q16 >> 1);
#pragma unroll
    for (int kk = 0; kk < 32; ++kk) {
      s16x8 v;
#pragma unroll
      for (int e = 0; e < 8; ++e) v[e] = (short)f2bf(Wp[kk * 32 + e]);
      wreg[kk] = v;
    }
  } else {
    const int half = w & 1;
    const float* Wp = ((s == 0) ? WTc : WFc) + 393216
                    + ((size_t)(j0 + half * 16 + l15)) * 768 + (q16 >> 1);
#pragma unroll
    for (int kk = 0; kk < 24; ++kk) {
      s16x8 v;
#pragma unroll
      for (int e = 0; e < 8; ++e) v[e] = (short)f2bf(Wp[kk * 32 + e]);
      wreg[kk] = v;
    }
  }

  // ---- per-thread elementwise constants + register-resident cell state ----
  const int ro = tid >> 4;           // row 0..31
  const int cc0 = (tid & 15) * 2;    // col pair 0..30
  const int ehalf = cc0 >> 4;
  const int ec16 = cc0 & 15;
  float bfv0, bfv1, biv0, biv1, bov0, bov1, bcv0, bcv1;
  {
    const float* bg = ((s == 0) ? bTg : bFg) + 1536;
    const float* bc = ((s == 0) ? bTc : bFc) + 512;
    int col = j0 + cc0;
    bfv0 = bg[col];        bfv1 = bg[col + 1];
    biv0 = bg[512 + col];  biv1 = bg[513 + col];
    bov0 = bg[1024 + col]; bov1 = bg[1025 + col];
    bcv0 = bc[col];        bcv1 = bc[col + 1];
  }
  float C0 = 0.f, C1 = 0.f;

  for (int t = 0; t < 128; ++t) {
    if (t) grid_sync(bar);
    const int cur = t & 1;

    // ---- stage A tile: [32 rows][xy 1024B | h 1024B], XOR-swizzled ----
    {
      const char* xySrc = (const char*)(xyT + ((size_t)(t * 256 + m0)) * 512);
      const char* hSrc = (const char*)(hbuf + ((size_t)((cur * 2 + s) * 256 + m0)) * 512);
#pragma unroll
      for (int i = 0; i < 8; ++i) {
        int g = tid + i * NTHR;
        int r = g >> 7;
        int cb = (g & 127) * 16;
        uint4 v = (cb < 1024) ? *(const uint4*)(xySrc + (size_t)r * 1024 + cb)
                              : *(const uint4*)(hSrc + (size_t)r * 1024 + (cb - 1024));
        *(uint4*)(smem + r * 2048 + (cb ^ ((r & 7) << 4))) = v;
      }
    }
    __syncthreads();

    // ---- GEMM: 2 Mtiles x (per-wave 16-col panel) ----
    f32x4 acc0 = {0.f, 0.f, 0.f, 0.f};
    f32x4 acc1 = {0.f, 0.f, 0.f, 0.f};
    {
      const int sw = (l15 & 7) << 4;
      const char* base0 = smem + l15 * 2048;
      const char* base1 = smem + (16 + l15) * 2048;
      if (isGate) {
#pragma unroll
        for (int kk = 0; kk < 32; ++kk) {
          int c = (kk * 64 + q16) ^ sw;
          s16x8 a0 = *(const s16x8*)(base0 + c);
          s16x8 a1 = *(const s16x8*)(base1 + c);
          acc0 = __builtin_amdgcn_mfma_f32_16x16x32_bf16(
              __builtin_bit_cast(bf16x8, a0), __builtin_bit_cast(bf16x8, wreg[kk]), acc0, 0, 0, 0);
          acc1 = __builtin_amdgcn_mfma_f32_16x16x32_bf16(
              __builtin_bit_cast(bf16x8, a1), __builtin_bit_cast(bf16x8, wreg[kk]), acc1, 0, 0, 0);
        }
      } else {
#pragma unroll
        for (int kk = 0; kk < 24; ++kk) {
          int c = ((((kk < 8) ? (s * 512 + kk * 64) : (512 + kk * 64)) + q16)) ^ sw;
          s16x8 a0 = *(const s16x8*)(base0 + c);
          s16x8 a1 = *(const s16x8*)(base1 + c);
          acc0 = __builtin_amdgcn_mfma_f32_16x16x32_bf16(
              __builtin_bit_cast(bf16x8, a0), __builtin_bit_cast(bf16x8, wreg[kk]), acc0, 0, 0, 0);
          acc1 = __builtin_amdgcn_mfma_f32_16x16x32_bf16(
              __builtin_bit_cast(bf16x8, a1), __builtin_bit_cast(bf16x8, wreg[kk]), acc1, 0, 0, 0);
        }
      }
    }
    // C/D layout (m89-verified): col = lane&15, row = (lane>>4)*4 + reg
#pragma unroll
    for (int rg = 0; rg < 4; ++rg) {
      sAcc[(w << 9) + ((q16 >> 2) + rg) * 16 + l15] = acc0[rg];
      sAcc[(w << 9) + (16 + (q16 >> 2) + rg) * 16 + l15] = acc1[rg];
    }
    __syncthreads();

    // ---- elementwise LSTM update (C in registers) ----
    {
      const float2 pf = *(const float2*)&sAcc[(ehalf << 9) + ro * 16 + ec16];
      const float2 pi = *(const float2*)&sAcc[((2 + ehalf) << 9) + ro * 16 + ec16];
      const float2 po = *(const float2*)&sAcc[((4 + ehalf) << 9) + ro * 16 + ec16];
      const float2 pc = *(const float2*)&sAcc[((6 + ehalf) << 9) + ro * 16 + ec16];
      float f0 = sigm(pf.x + bfv0), f1 = sigm(pf.y + bfv1);
      float i0 = sigm(pi.x + biv0), i1 = sigm(pi.y + biv1);
      float o0 = sigm(po.x + bov0), o1 = sigm(po.y + bov1);
      float c0 = tanhf_(pc.x + bcv0), c1 = tanhf_(pc.y + bcv1);
      C0 = f0 * C0 + i0 * c0;
      C1 = f1 * C1 + i1 * c1;
      float h0 = o0 * tanhf_(C0);
      float h1 = o1 * tanhf_(C1);
      uint hp = (uint)f2bf(h0) | (((uint)f2bf(h1)) << 16);
      *(uint*)(hbuf + ((size_t)(((cur ^ 1) * 2 + s) * 256 + m0 + ro)) * 512 + j0 + cc0) = hp;
      *(uint*)(hist + (((size_t)s * 128 + t) * 256 + m0 + ro) * 512 + j0 + cc0) = hp;
    }
  }
}

// ---------------- BN stats: per (s,t,h): scale/shift over batch ----------------
__global__ void bnstat_k(const ushort* __restrict__ hist,
                         const float* __restrict__ gT, const float* __restrict__ beT,
                         const float* __restrict__ gF, const float* __restrict__ beF,
                         float* __restrict__ scale, float* __restrict__ shift) {
  const int t = blockIdx.x >> 1, s = blockIdx.x & 1;
  const int tid = threadIdx.x;
  const ushort* hp = hist + ((size_t)s * 128 + t) * 256 * 512;
  const float* gp = (s ? gF : gT) + 512;
  const float* bp = (s ? beF : beT) + 512;
#pragma unroll
  for (int hh = 0; hh < 2; ++hh) {
    const int h = tid + hh * 256;
    float sum = 0.f, sq = 0.f;
#pragma unroll 8
    for (int b = 0; b < 256; ++b) {
      float v = bf2f(hp[(size_t)b * 512 + h]);
      sum += v;
      sq += v * v;
    }
    float mu = sum * 0.00390625f;
    float var = sq * 0.00390625f - mu * mu;  // biased, matches reference
    float sc = (1.0f / sqrtf(var + 1e-5f)) * gp[h];
    size_t o = ((size_t)s * 128 + t) * 512 + h;
    scale[o] = sc;
    shift[o] = bp[h] - mu * sc;
  }
}

// ---------------- BN apply + transpose [s][t][b][h] -> out[b][h][t] ----------------
__global__ void bnwrite_k(const ushort* __restrict__ hist, const float* __restrict__ scale,
                          const float* __restrict__ shift, float* __restrict__ out) {
  __shared__ float sT[64 * 129];
  const int bid = blockIdx.x;
  const int hc = bid & 7, b = (bid >> 3) & 255, s = bid >> 11;
  const int h0 = hc * 64;
  const int tid = threadIdx.x;
  const int hh = tid & 63, tq = tid >> 6;
#pragma unroll 4
  for (int tc = 0; tc < 32; ++tc) {
    const int t = tc * 4 + tq;
    const size_t so = ((size_t)s * 128 + t) * 512 + h0 + hh;
    float v = bf2f(hist[(((size_t)s * 128 + t) * 256 + b) * 512 + h0 + hh]);
    sT[hh * 129 + t] = v * scale[so] + shift[so];
  }
  __syncthreads();
  const int t2 = tid & 127, hq = tid >> 7;
#pragma unroll 4
  for (int i = 0; i < 32; ++i) {
    const int h = i * 2 + hq;
    out[(size_t)s * 16777216 + ((size_t)b * 512 + h0 + h) * 128 + t2] = sT[h * 129 + t2];
  }
}

extern "C" void kernel_launch(void* const* d_in, const int* in_sizes, int n_in,
                              void* d_out, int out_size, void* d_ws, size_t ws_size,
                              hipStream_t stream) {
  const float* inputx = (const float*)d_in[0];
  const float* inputy = (const float*)d_in[1];
  const float* WTg = (const float*)d_in[2];
  const float* bTg = (const float*)d_in[3];
  const float* WFg = (const float*)d_in[4];
  const float* bFg = (const float*)d_in[5];
  const float* WTc = (const float*)d_in[6];
  const float* bTc = (const float*)d_in[7];
  const float* WFc = (const float*)d_in[8];
  const float* bFc = (const float*)d_in[9];
  const float* gT = (const float*)d_in[10];
  const float* beT = (const float*)d_in[11];
  const float* gF = (const float*)d_in[12];
  const float* beF = (const float*)d_in[13];
  float* out = (float*)d_out;

  char* ws = (char*)d_ws;
  ushort* xyT = (ushort*)ws;                    // 33,554,432 B
  ushort* hbuf = (ushort*)(ws + 33554432);      //  1,048,576 B (ping-pong h, both streams)
  ushort* hist = (ushort*)(ws + 34603008);      // 67,108,864 B  [s][t][b][h]
  float* scale = (float*)(ws + 101711872);      //    524,288 B
  float* shift = (float*)(ws + 102236160);      //    524,288 B
  uint* bar = (uint*)(ws + 102760448);          //        256 B

  init_k<<<512, 256, 0, stream>>>((uint*)hbuf, bar);
  xyt_k<<<65536, 256, 0, stream>>>(inputx, inputy, xyT);

  hipFuncSetAttribute((const void*)seq_k, hipFuncAttributeMaxDynamicSharedMemorySize, 81920);
  void* args[12];
  void* p0 = (void*)xyT;  // keep pointer lvalues for kernelParams
  args[0] = &xyT; args[1] = &hbuf; args[2] = &hist;
  args[3] = &WTg; args[4] = &WFg; args[5] = &WTc; args[6] = &WFc;
  args[7] = &bTg; args[8] = &bFg; args[9] = &bTc; args[10] = &bFc;
  args[11] = &bar;
  (void)p0;
  hipLaunchCooperativeKernel((const void*)seq_k, dim3(NBLK), dim3(NTHR), args, 81920, stream);

  bnstat_k<<<256, 256, 0, stream>>>(hist, gT, beT, gF, beF, scale, shift);
  bnwrite_k<<<4096, 256, 0, stream>>>(hist, scale, shift, out);
}